// Round 3
// baseline (96.277 us; speedup 1.0000x reference)
//
#include <hip/hip_runtime.h>

// ---------------------------------------------------------------------------
// out[b,o] = sum_{f,p} x0[b,f]*x[b,p]*W[o,f,p] + bias[o]
//   == GEMM C[4096,256] = A[4096,16384] * W^T,  A[b,f*128+p] = x0[b,f]*x[b,p]
// R3: R2 structure with the NaN bug fixed (s_h[4..7] were never loaded —
// PHASE(1,0) now receives shload). 8-phase-style schedule (T3+T4+T5).
// BM=256 x BN=256, BK=64, splitK=16 -> 256 blocks (1/CU), 512 thr = 8 waves
// (2Mx4N). x persistent in LDS (64KB); W streamed via 5-slot 16KB half-tile
// ring with counted vmcnt(2) (never 0 in steady state). x0 kept f32
// transposed [8][256] (conflict-free broadcast reads). f32 atomics split-K.
// ---------------------------------------------------------------------------

typedef _Float16 f16x8 __attribute__((ext_vector_type(8)));
typedef float    f32x4 __attribute__((ext_vector_type(4)));

#define WS_WF_OFF 0
#define WS_XF_OFF 8388608
#define WS_NEEDED 9437184

__device__ __forceinline__ void gl_lds16(const void* g, void* l) {
  __builtin_amdgcn_global_load_lds(
      (const __attribute__((address_space(1))) void*)g,
      (__attribute__((address_space(3))) void*)l, 16, 0, 0);
}

#define BAR()     asm volatile("s_barrier" ::: "memory")
#define VMCNT2()  asm volatile("s_waitcnt vmcnt(2)" ::: "memory")
#define VMCNT0()  asm volatile("s_waitcnt vmcnt(0)" ::: "memory")
#define VMCNT14() asm volatile("s_waitcnt vmcnt(14)" ::: "memory")
#define LGKM0()   asm volatile("s_waitcnt lgkmcnt(0)" ::: "memory")

// ------------------------------ prep kernel --------------------------------
// [0,524288): W f32->f16 + seg-swizzle; [524288,589824): x f32->f16 + swizzle;
// [589824,851968): out = bias (float4 groups).
__global__ __launch_bounds__(256) void prep_kernel(
    const float* __restrict__ x, const float* __restrict__ W,
    const float* __restrict__ bias, _Float16* __restrict__ Wf,
    _Float16* __restrict__ Xf, float* __restrict__ out)
{
  int i = blockIdx.x * 256 + threadIdx.x;
  if (i < 524288) {
    int o = i >> 11, k8 = i & 2047;
    int kk = k8 >> 3, seg = k8 & 7;
    const float* s = W + ((size_t)o << 14) + ((size_t)k8 << 3);
    f16x8 h;
#pragma unroll
    for (int e = 0; e < 8; ++e) h[e] = (_Float16)s[e];
    int segp = seg ^ (o & 7);
    *(f16x8*)(Wf + ((size_t)o << 14) + kk * 64 + segp * 8) = h;
  } else if (i < 589824) {
    int j = i - 524288;
    int r = j >> 4, seg = j & 15;
    const float* s = x + r * 128 + seg * 8;
    f16x8 h;
#pragma unroll
    for (int e = 0; e < 8; ++e) h[e] = (_Float16)s[e];
    int segp = seg ^ (r & 7);
    *(f16x8*)(Xf + r * 128 + segp * 8) = h;
  } else {
    int j = i - 589824;                     // float4 idx into out[4096][256]
    int c = (j * 4) & 255;
    ((float4*)out)[j] = *(const float4*)(bias + c);
  }
}

// ------------------------------ GEMM kernel --------------------------------
// Half-tile H_j (j=2*kk+oh): o-half oh of K-step kk, 16KB, slot j%5 in ring.
// KSTEP(kk) phases p0,p1 stage H_{2kk+3} (slot sbase+3); p2,p3 stage
// H_{2kk+4} (slot sbase+4). vmcnt(2) at end of p3: everything through
// H_{2kk+3} complete -> KSTEP(kk+1)'s reads (H_{2kk+2},H_{2kk+3}) are safe.
__global__ __launch_bounds__(512, 2) void gemm_kernel(
    const _Float16* __restrict__ Wf, const _Float16* __restrict__ Xf,
    const float* __restrict__ x0, float* __restrict__ out)
{
  __shared__ __align__(16) char smem[155648];
  char*  x_s    = smem;                       // 65536  : x [256][128] f16 swz
  char*  w_ring = smem + 65536;               // 81920  : 5 x 16KB W half-tiles
  float* x0t    = (float*)(smem + 147456);    // 8192   : x0^T [8][256] f32

  const int bid = blockIdx.x;
  const int mb  = bid >> 4;
  const int sk  = bid & 15;
  const int sk16 = sk * 16;

  const int t    = threadIdx.x;
  const int lane = t & 63;
  const int wv   = t >> 6;
  const int wm   = wv >> 2;          // 0..1 : M half (128 rows)
  const int wn   = wv & 3;           // 0..3 : N quarter (64 cols)
  const int oh   = wn >> 1;          // which W o-half this wave reads
  const int wnoff = (wn & 1) * 8192; // o_local offset within half-tile
  const int lr   = lane & 15;
  const int lg   = lane >> 4;
  const int swz  = lr & 7;
  const int t16  = t * 16;

  // per-lane precomputed seg byte-offsets (k-seg XOR swizzle)
  const int sv0 = ((0  + lg) ^ swz) * 16;
  const int sv1 = ((4  + lg) ^ swz) * 16;
  const int sv2 = ((8  + lg) ^ swz) * 16;
  const int sv3 = ((12 + lg) ^ swz) * 16;
  const int xrow_base = (wm * 128 + lr) * 256;   // byte base of lane's x row
  const int lrB = lr * 128;
  const int x0row = wm * 128 + lr;

  // staging per-lane base: thread covers o_sub=t>>3, 16B seg t&7
  const char* sW = (const char*)Wf + (size_t)(t >> 3) * 32768 + (t & 7) * 16;

  // ---- prologue ----
  const int r0 = t >> 1, hf = t & 1;
  const float4 x0v = *(const float4*)(x0 + (size_t)(mb * 256 + r0) * 128 + sk * 8 + hf * 4);

  const char* XfB = (const char*)Xf + (size_t)mb * 65536;
#pragma unroll
  for (int i = 0; i < 8; ++i)
    gl_lds16(XfB + i * 8192 + t16, x_s + i * 8192 + t16);

  const int kb0 = sk16 << 7, kb1 = (sk16 + 1) << 7;
  gl_lds16(sW + 0 * 32768   + kb0, w_ring + 0 * 16384 + 0    + t16);  // H0 r0
  gl_lds16(sW + 64 * 32768  + kb0, w_ring + 0 * 16384 + 8192 + t16);  // H0 r1
  gl_lds16(sW + 128 * 32768 + kb0, w_ring + 1 * 16384 + 0    + t16);  // H1 r0
  gl_lds16(sW + 192 * 32768 + kb0, w_ring + 1 * 16384 + 8192 + t16);  // H1 r1
  gl_lds16(sW + 0 * 32768   + kb1, w_ring + 2 * 16384 + 0    + t16);  // H2 r0
  gl_lds16(sW + 64 * 32768  + kb1, w_ring + 2 * 16384 + 8192 + t16);  // H2 r1

  VMCNT14();                                   // x0 float4 (oldest) retired
  x0t[(hf * 4 + 0) * 256 + r0] = x0v.x;
  x0t[(hf * 4 + 1) * 256 + r0] = x0v.y;
  x0t[(hf * 4 + 2) * 256 + r0] = x0v.z;
  x0t[(hf * 4 + 3) * 256 + r0] = x0v.w;
  VMCNT2();                                    // x rounds + H0,H1 done
  LGKM0();
  BAR();

  f32x4 acc[8][4] = {};
  f16x8 av[4][2], bv[2][2];
  _Float16 s_h[8];

#define PHASE(MH, NH, SHLOAD, STAGE_EN, STAGE_SLOT, STAGE_KB, STAGE_OHRR, STAGE_DST, VMF) \
  { \
    if (NH == 0) { \
      _Pragma("unroll") \
      for (int i = 0; i < 4; ++i) { \
        if (SHLOAD) s_h[MH * 4 + i] = (_Float16)x0t[fl * 256 + x0row + (MH * 4 + i) * 16]; \
        const char* ap = x_s + xrow_base + (MH * 4 + i) * 4096; \
        av[i][0] = *(const f16x8*)(ap + sA0) * s_h[MH * 4 + i]; \
        av[i][1] = *(const f16x8*)(ap + sA1) * s_h[MH * 4 + i]; \
      } \
    } \
    _Pragma("unroll") \
    for (int j = 0; j < 2; ++j) { \
      const char* bp = wrd + (NH * 2 + j) * 2048 + lrB; \
      bv[j][0] = *(const f16x8*)(bp + sv0); \
      bv[j][1] = *(const f16x8*)(bp + sv1); \
    } \
    if (STAGE_EN) \
      gl_lds16(sW + (STAGE_OHRR) + (STAGE_KB), \
               w_ring + (STAGE_SLOT) * 16384 + (STAGE_DST) + t16); \
    BAR(); \
    __builtin_amdgcn_sched_barrier(0); \
    __builtin_amdgcn_s_setprio(1); \
    _Pragma("unroll") \
    for (int i = 0; i < 4; ++i) { \
      _Pragma("unroll") \
      for (int j = 0; j < 2; ++j) { \
        acc[MH * 4 + i][NH * 2 + j] = __builtin_amdgcn_mfma_f32_16x16x32_f16( \
            av[i][0], bv[j][0], acc[MH * 4 + i][NH * 2 + j], 0, 0, 0); \
        acc[MH * 4 + i][NH * 2 + j] = __builtin_amdgcn_mfma_f32_16x16x32_f16( \
            av[i][1], bv[j][1], acc[MH * 4 + i][NH * 2 + j], 0, 0, 0); \
      } \
    } \
    __builtin_amdgcn_s_setprio(0); \
    VMF; \
    BAR(); \
  }

#define KSTEP(KK, S01, S23, VMF) \
  { \
    const int kk_ = (KK); \
    const int par = kk_ & 1; \
    const int fl  = kk_ >> 1; \
    const int sA0 = par ? sv2 : sv0; \
    const int sA1 = par ? sv3 : sv1; \
    int slotR = sbase + oh;  if (slotR >= 5) slotR -= 5; \
    const char* wrd = w_ring + slotR * 16384 + wnoff; \
    int slotA = sbase + 3;   if (slotA >= 5) slotA -= 5; \
    int slotB = sbase + 4;   if (slotB >= 5) slotB -= 5; \
    const int kbA = (sk16 + kk_ + 1) << 7; \
    const int kbB = (sk16 + kk_ + 2) << 7; \
    const bool shload = (par == 0); \
    PHASE(0, 0, shload, S01, slotA, kbA, 128 * 32768, 0,    ;) \
    PHASE(0, 1, false,  S01, slotA, kbA, 192 * 32768, 8192, ;) \
    PHASE(1, 0, shload, S23, slotB, kbB, 0 * 32768,   0,    ;) \
    PHASE(1, 1, false,  S23, slotB, kbB, 64 * 32768,  8192, VMF) \
  }

  int sbase = 0;
#pragma unroll 2
  for (int kk = 0; kk < 14; ++kk) {
    KSTEP(kk, true, true, VMCNT2());
    sbase += 2; if (sbase >= 5) sbase -= 5;
  }
  KSTEP(14, true, false, VMCNT0());
  sbase += 2; if (sbase >= 5) sbase -= 5;
  KSTEP(15, false, false, ;);

#undef KSTEP
#undef PHASE

  // ---- epilogue: split-K accumulate (out pre-initialized to bias) ----
  // C/D layout: col = lane&15, row = (lane>>4)*4 + reg
  float* op = out + (size_t)(mb * 256 + wm * 128 + lg * 4) * 256 + wn * 64 + lr;
#pragma unroll
  for (int mI = 0; mI < 8; ++mI)
#pragma unroll
    for (int nI = 0; nI < 4; ++nI)
#pragma unroll
      for (int rr = 0; rr < 4; ++rr)
        unsafeAtomicAdd(op + (size_t)(mI * 16 + rr) * 256 + nI * 16,
                        acc[mI][nI][rr]);
}

// --------------------------- fallback (no ws) ------------------------------
__global__ __launch_bounds__(256) void naive_kernel(
    const float* __restrict__ x0, const float* __restrict__ x,
    const float* __restrict__ W, const float* __restrict__ bias,
    float* __restrict__ out)
{
  __shared__ float x0_s[16][128];
  __shared__ float x_s[16][128];
  const int tid = threadIdx.x;
  const int b0  = blockIdx.x * 16;
  for (int i = tid; i < 16 * 128; i += 256) {
    int bb = i >> 7, c = i & 127;
    x0_s[bb][c] = x0[(size_t)(b0 + bb) * 128 + c];
    x_s[bb][c]  = x[(size_t)(b0 + bb) * 128 + c];
  }
  __syncthreads();
  const int lane = tid & 63, wv = tid >> 6;
  for (int o = wv; o < 256; o += 4) {
    float acc[16];
#pragma unroll
    for (int bb = 0; bb < 16; ++bb) acc[bb] = 0.f;
    for (int it = 0; it < 256; ++it) {
      int k = it * 64 + lane;
      float wval = W[(size_t)o * 16384 + k];
      int f = k >> 7, p = k & 127;
#pragma unroll
      for (int bb = 0; bb < 16; ++bb)
        acc[bb] += wval * (x0_s[bb][f] * x_s[bb][p]);
    }
#pragma unroll
    for (int bb = 0; bb < 16; ++bb) {
      float v = acc[bb];
      for (int off = 32; off; off >>= 1) v += __shfl_down(v, off);
      if (lane == 0) out[(size_t)(b0 + bb) * 256 + o] = v + bias[o];
    }
  }
}

// ------------------------------- launcher ----------------------------------
extern "C" void kernel_launch(void* const* d_in, const int* in_sizes, int n_in,
                              void* d_out, int out_size, void* d_ws,
                              size_t ws_size, hipStream_t stream)
{
  const float* x0   = (const float*)d_in[0];
  const float* x    = (const float*)d_in[1];
  const float* W    = (const float*)d_in[2];
  const float* bias = (const float*)d_in[3];
  float* out = (float*)d_out;

  if (ws_size >= (size_t)WS_NEEDED) {
    _Float16* Wf = (_Float16*)((char*)d_ws + WS_WF_OFF);
    _Float16* Xf = (_Float16*)((char*)d_ws + WS_XF_OFF);
    prep_kernel<<<3328, 256, 0, stream>>>(x, W, bias, Wf, Xf, out);
    gemm_kernel<<<256, 512, 0, stream>>>(Wf, Xf, x0, out);
  } else {
    naive_kernel<<<256, 256, 0, stream>>>(x0, x, W, bias, out);
  }
}

// Round 4
// 68.767 us; speedup vs baseline: 1.4000x; 1.4000x over previous
//
#include <hip/hip_runtime.h>

// ---------------------------------------------------------------------------
// out[b,o] = sum_{f,p} x0[b,f]*x[b,p]*W[o,f,p] + bias[o]
//   == GEMM C[4096,256] = A[4096,16384] * W^T,  A[b,f*128+p] = x0[b,f]*x[b,p]
// R4: barrier-free K-loop. A is rank-1 per row (x-frag * x0 scalar) and x
// repeats every 2 K-steps -> each wave's x slice lives in REGISTERS (16x
// f16x8, loaded once via swizzled LDS prologue). W (8 MB f16, L2-resident)
// is streamed per-step straight from global in an MFMA-fragment-ordered
// layout (prep writes it so each B-frag load is one coalesced dwordx4:
// 64 lanes x 16 B = 1 KB contiguous). Zero LDS ops / zero barriers in the
// K-loop -> no lockstep, no staging drain (R3 pathology), compiler pipelines
// freely. 256 blocks (32 mb x 8 sk), 512 thr = 8 waves (2m x 4n), wave=64x64,
// 32 K-steps of BK=64. Split-K=8 via f32 atomics onto bias-initialized out.
// ---------------------------------------------------------------------------

typedef _Float16 f16x8 __attribute__((ext_vector_type(8)));
typedef float    f32x4 __attribute__((ext_vector_type(4)));

#define WS_WT_OFF 0
#define WS_XF_OFF 8388608
#define WS_NEEDED 9437184

__device__ __forceinline__ void gl_lds16(const void* g, void* l) {
  __builtin_amdgcn_global_load_lds(
      (const __attribute__((address_space(1))) void*)g,
      (__attribute__((address_space(3))) void*)l, 16, 0, 0);
}

// ------------------------------ prep kernel --------------------------------
// [0,524288): W f32->f16 into MFMA-fragment order:
//   k-step sg=k/64 (0..255), o-group g=o/16, seg=(k%64)/8, lane-row o%15..
//   WT byte addr = (sg*16 + o/16)*2048 + seg*256 + (o%16)*16 + (k%8)*2
//   -> a wave's B-frag (o-range 16, k-range 32) = 1 KB contiguous.
// [524288,589824): x f32->f16 + XOR-seg swizzle (reader-matched).
// [589824,851968): out = bias (float4 groups).
__global__ __launch_bounds__(256) void prep_kernel(
    const float* __restrict__ x, const float* __restrict__ W,
    const float* __restrict__ bias, char* __restrict__ WT,
    _Float16* __restrict__ Xf, float* __restrict__ out)
{
  int i = blockIdx.x * 256 + threadIdx.x;
  if (i < 524288) {
    int o = i >> 11, k8 = i & 2047;        // k8: 8-elem k-granule within row o
    const float* s = W + ((size_t)o << 14) + ((size_t)k8 << 3);
    f16x8 h;
#pragma unroll
    for (int e = 0; e < 8; ++e) h[e] = (_Float16)s[e];
    int sg  = k8 >> 3;                     // global k-step 0..255
    int seg = k8 & 7;
    char* dst = WT + ((size_t)(sg * 16 + (o >> 4))) * 2048 + seg * 256 + (o & 15) * 16;
    *(f16x8*)dst = h;
  } else if (i < 589824) {
    int j = i - 524288;
    int r = j >> 4, seg = j & 15;
    const float* s = x + r * 128 + seg * 8;
    f16x8 h;
#pragma unroll
    for (int e = 0; e < 8; ++e) h[e] = (_Float16)s[e];
    int segp = seg ^ (r & 7);
    *(f16x8*)(Xf + r * 128 + segp * 8) = h;
  } else {
    int j = i - 589824;                    // float4 idx into out[4096][256]
    int c = (j * 4) & 255;
    ((float4*)out)[j] = *(const float4*)(bias + c);
  }
}

// ------------------------------ GEMM kernel --------------------------------
__global__ __launch_bounds__(512, 2) void gemm_kernel(
    const char* __restrict__ WT, const _Float16* __restrict__ Xf,
    const float* __restrict__ x0, float* __restrict__ out)
{
  __shared__ __align__(16) char x_s[32768];   // x tile [128 rows][128 p] f16 swz

  const int bid = blockIdx.x;
  const int mb  = bid >> 3;          // 0..31 : 128-row block
  const int sk  = bid & 7;           // 0..7  : split-K chunk (16 f-values)

  const int t   = threadIdx.x;
  const int l   = t & 63;
  const int wv  = t >> 6;
  const int wm  = wv >> 2;           // 0..1 : M half (64 rows each)
  const int wn  = wv & 3;            // 0..3 : N quarter (64 cols)
  const int lr  = l & 15;
  const int lg  = l >> 4;
  const int swz = lr & 7;

  // ---- prologue: stage x tile (32 KB) via gl_lds16, then regs ----
  const char* XfB = (const char*)Xf + (size_t)mb * 32768;
#pragma unroll
  for (int i = 0; i < 4; ++i)
    gl_lds16(XfB + i * 8192 + t * 16, x_s + i * 8192 + t * 16);
  __syncthreads();

  // xr[mI][p-half][t]: A-frag source, row = wm*64 + mI*16 + lr,
  // k-window seg = (half*8 + t*4 + lg) ^ swz (prep-matched XOR swizzle).
  f16x8 xr[4][2][2];
  const int rowb = (wm * 64 + lr) * 256;
#pragma unroll
  for (int m = 0; m < 4; ++m)
#pragma unroll
    for (int h = 0; h < 2; ++h)
#pragma unroll
      for (int tt = 0; tt < 2; ++tt) {
        int seg = (h * 8 + tt * 4 + lg) ^ swz;
        xr[m][h][tt] = *(const f16x8*)(x_s + rowb + m * 4096 + seg * 16);
      }

  // per-lane x0 row pointer (f window of this split-K chunk)
  const float* x0p = x0 + (size_t)(mb * 128 + wm * 64 + lr) * 128 + sk * 16;
  // per-lane W stream pointer: o-group = wn*4, k-step base = sk*32
  const char* wt = WT + ((size_t)(sk * 32) * 16 + wn * 4) * 2048 + l * 16;

  f32x4 acc[4][4] = {};
  _Float16 sh[4];

#pragma unroll 2
  for (int s = 0; s < 32; ++s) {
    const int ph = s & 1;              // p-half (f fixed for 2 steps)
    if (!ph) {
#pragma unroll
      for (int m = 0; m < 4; ++m)
        sh[m] = (_Float16)x0p[(size_t)m * 2048 + (s >> 1)];
    }
    f16x8 bw[4][2];
#pragma unroll
    for (int nI = 0; nI < 4; ++nI)
#pragma unroll
      for (int tt = 0; tt < 2; ++tt)
        bw[nI][tt] = *(const f16x8*)(wt + nI * 2048 + tt * 1024);

#pragma unroll
    for (int m = 0; m < 4; ++m) {
#pragma unroll
      for (int tt = 0; tt < 2; ++tt) {
        f16x8 av = xr[m][ph][tt] * sh[m];   // A = x0 scalar * x frag
#pragma unroll
        for (int nI = 0; nI < 4; ++nI)
          acc[m][nI] = __builtin_amdgcn_mfma_f32_16x16x32_f16(
              av, bw[nI][tt], acc[m][nI], 0, 0, 0);
      }
    }
    wt += 32768;                       // next k-step (16 o-groups * 2 KB)
  }

  // ---- epilogue: split-K accumulate (out pre-initialized to bias) ----
  // C/D layout: col = lane&15, row = (lane>>4)*4 + reg
  float* op = out + (size_t)(mb * 128 + wm * 64 + lg * 4) * 256 + wn * 64 + lr;
#pragma unroll
  for (int m = 0; m < 4; ++m)
#pragma unroll
    for (int nI = 0; nI < 4; ++nI)
#pragma unroll
      for (int r = 0; r < 4; ++r)
        unsafeAtomicAdd(op + (size_t)(m * 16 + r) * 256 + nI * 16,
                        acc[m][nI][r]);
}

// --------------------------- fallback (no ws) ------------------------------
__global__ __launch_bounds__(256) void naive_kernel(
    const float* __restrict__ x0, const float* __restrict__ x,
    const float* __restrict__ W, const float* __restrict__ bias,
    float* __restrict__ out)
{
  __shared__ float x0_s[16][128];
  __shared__ float x_s[16][128];
  const int tid = threadIdx.x;
  const int b0  = blockIdx.x * 16;
  for (int i = tid; i < 16 * 128; i += 256) {
    int bb = i >> 7, c = i & 127;
    x0_s[bb][c] = x0[(size_t)(b0 + bb) * 128 + c];
    x_s[bb][c]  = x[(size_t)(b0 + bb) * 128 + c];
  }
  __syncthreads();
  const int lane = tid & 63, wv = tid >> 6;
  for (int o = wv; o < 256; o += 4) {
    float acc[16];
#pragma unroll
    for (int bb = 0; bb < 16; ++bb) acc[bb] = 0.f;
    for (int it = 0; it < 256; ++it) {
      int k = it * 64 + lane;
      float wval = W[(size_t)o * 16384 + k];
      int f = k >> 7, p = k & 127;
#pragma unroll
      for (int bb = 0; bb < 16; ++bb)
        acc[bb] += wval * (x0_s[bb][f] * x_s[bb][p]);
    }
#pragma unroll
    for (int bb = 0; bb < 16; ++bb) {
      float v = acc[bb];
      for (int off = 32; off; off >>= 1) v += __shfl_down(v, off);
      if (lane == 0) out[(size_t)(b0 + bb) * 256 + o] = v + bias[o];
    }
  }
}

// ------------------------------- launcher ----------------------------------
extern "C" void kernel_launch(void* const* d_in, const int* in_sizes, int n_in,
                              void* d_out, int out_size, void* d_ws,
                              size_t ws_size, hipStream_t stream)
{
  const float* x0   = (const float*)d_in[0];
  const float* x    = (const float*)d_in[1];
  const float* W    = (const float*)d_in[2];
  const float* bias = (const float*)d_in[3];
  float* out = (float*)d_out;

  if (ws_size >= (size_t)WS_NEEDED) {
    char*     WT = (char*)d_ws + WS_WT_OFF;
    _Float16* Xf = (_Float16*)((char*)d_ws + WS_XF_OFF);
    prep_kernel<<<3328, 256, 0, stream>>>(x, W, bias, WT, Xf, out);
    gemm_kernel<<<256, 512, 0, stream>>>(WT, Xf, x0, out);
  } else {
    naive_kernel<<<256, 256, 0, stream>>>(x0, x, W, bias, out);
  }
}